// Round 6
// baseline (16.929 us; speedup 1.0000x reference)
//
#include <hip/hip_runtime.h>

// DWA_CNN: B=32, T=2048, C=128, K=3, F=8, P=2046
// v5b: = v5 with sqrtf fix. 128-thr/32-row blocks (2208 blocks, ~all
//     co-resident), cvt_pk bf16 packing, norms from staged regs/fragments,
//     G aliased onto Xs LDS, branchless register-LUT backtrace.

#define TT   30
#define RWS  32
#define GSTR 27
#define BIGV 1234567891011.0f

typedef __attribute__((ext_vector_type(8))) short short8v;
typedef __attribute__((ext_vector_type(4))) float f32x4;

static __device__ inline unsigned pk2(float lo, float hi) {
  unsigned r;
  asm("v_cvt_pk_bf16_f32 %0, %1, %2" : "=v"(r) : "v"(lo), "v"(hi));
  return r;
}
static __device__ inline float bf2f(unsigned short h) {
  return __uint_as_float(((unsigned)h) << 16);
}
// u16 index in a swizzled [row][128] bf16 tile (same swizzle as v4)
static __device__ inline int swzi(int row, int c) {
  return row * 128 + (((c >> 3) ^ (row & 7)) << 3) + (c & 7);
}

__global__ __launch_bounds__(128, 4) void dwa_cnn_kernel(
    const float* __restrict__ x, const float* __restrict__ w,
    const float* __restrict__ bias, float* __restrict__ out)
{
  constexpr int T = 2048, C = 128, P = 2046;

  __shared__ alignas(16) unsigned short Xs[RWS * 128];  // 8 KB; aliased as G later
  __shared__ alignas(16) unsigned short Wb[RWS * 128];  // 8 KB (rows 24..31 zero)
  __shared__ float WN[24];
  __shared__ float BI[8];
  float* G = reinterpret_cast<float*>(Xs);              // [32][GSTR]: dots + xn

  const int tid  = threadIdx.x;
  const int b    = blockIdx.y;
  const int p0   = blockIdx.x * TT;
  const int wave = tid >> 6;
  const int lane = tid & 63;

  const float breg = (tid < 8) ? bias[tid] : 0.f;

  // ---- x load: thread = (row, quarter); 8x dwordx4, coalesced ----
  const int srow = tid >> 2, c0 = (tid & 3) * 32;
  const int grow = (p0 + srow < T) ? (p0 + srow) : (T - 1);
  const float* xr = &x[((size_t)b * T + grow) * C + c0];
  float4 xv[8];
  #pragma unroll
  for (int m = 0; m < 8; ++m) xv[m] = *(const float4*)(xr + m * 4);

  // ---- w -> Wb (bf16 swizzled); 6x coalesced dwordx4 per thread ----
  #pragma unroll
  for (int j = 0; j < 6; ++j) {
    const int i4 = j * 512 + tid * 4;
    const float4 wv = *(const float4*)&w[i4];
    const int k = i4 >> 10, c = (i4 >> 3) & 127, f0 = i4 & 7;
    const int q = k * 8 + f0;
    Wb[swzi(q + 0, c)] = (unsigned short)pk2(wv.x, wv.x);
    Wb[swzi(q + 1, c)] = (unsigned short)pk2(wv.y, wv.y);
    Wb[swzi(q + 2, c)] = (unsigned short)pk2(wv.z, wv.z);
    Wb[swzi(q + 3, c)] = (unsigned short)pk2(wv.w, wv.w);
  }
  { uint4 z = {0, 0, 0, 0}; *(uint4*)&Wb[3072 + tid * 8] = z; }  // rows 24..31 = 0

  // ---- fp32 row-norm partial + pack x -> Xs ----
  float xn = 0.f;
  #pragma unroll
  for (int m = 0; m < 8; ++m)
    xn = fmaf(xv[m].x, xv[m].x, fmaf(xv[m].y, xv[m].y,
         fmaf(xv[m].z, xv[m].z, fmaf(xv[m].w, xv[m].w, xn))));
  #pragma unroll
  for (int m = 0; m < 4; ++m) {
    uint4 pkv;
    pkv.x = pk2(xv[2*m].x,   xv[2*m].y);
    pkv.y = pk2(xv[2*m].z,   xv[2*m].w);
    pkv.z = pk2(xv[2*m+1].x, xv[2*m+1].y);
    pkv.w = pk2(xv[2*m+1].z, xv[2*m+1].w);
    *(uint4*)&Xs[swzi(srow, c0 + m * 8)] = pkv;
  }
  xn += __shfl_xor(xn, 1);
  xn += __shfl_xor(xn, 2);

  __syncthreads();  // Xs, Wb ready

  // ---- fragments (layouts as v4, validated) ----
  const int g = lane >> 4;
  const int arow = wave * 16 + (lane & 15);
  const int q0 = lane & 15;
  short8v af[4], b0f[4], b1f[4];
  #pragma unroll
  for (int kk = 0; kk < 4; ++kk) {
    const int oct = kk * 4 + g;
    af[kk]  = *(const short8v*)&Xs[swzi(arow,    oct * 8)];
    b0f[kk] = *(const short8v*)&Wb[swzi(q0,      oct * 8)];
    b1f[kk] = *(const short8v*)&Wb[swzi(q0 + 16, oct * 8)];
  }

  f32x4 acc0 = {0.f, 0.f, 0.f, 0.f}, acc1 = {0.f, 0.f, 0.f, 0.f};
  #pragma unroll
  for (int kk = 0; kk < 4; ++kk) {
    acc0 = __builtin_amdgcn_mfma_f32_16x16x32_bf16(af[kk], b0f[kk], acc0, 0, 0, 0);
    acc1 = __builtin_amdgcn_mfma_f32_16x16x32_bf16(af[kk], b1f[kk], acc1, 0, 0, 0);
  }

  // ---- WN from B-fragments (wave 0 only) ----
  float wn0 = 0.f, wn1 = 0.f;
  if (wave == 0) {
    #pragma unroll
    for (int kk = 0; kk < 4; ++kk) {
      #pragma unroll
      for (int e = 0; e < 8; ++e) {
        const float v0 = bf2f((unsigned short)b0f[kk][e]);
        wn0 = fmaf(v0, v0, wn0);
        const float v1 = bf2f((unsigned short)b1f[kk][e]);
        wn1 = fmaf(v1, v1, wn1);
      }
    }
    wn0 += __shfl_xor(wn0, 16); wn0 += __shfl_xor(wn0, 32);
    wn1 += __shfl_xor(wn1, 16); wn1 += __shfl_xor(wn1, 32);
  }

  __syncthreads();  // all Xs/Wb reads done -> Xs reusable as G

  // ---- G writes: C/D layout col=lane&15, row=(lane>>4)*4+reg [m89] ----
  {
    const int col = lane & 15, rq = (lane >> 4) * 4;
    #pragma unroll
    for (int r = 0; r < 4; ++r)
      G[(wave * 16 + rq + r) * GSTR + col] = acc0[r];
    if (col < 8) {
      #pragma unroll
      for (int r = 0; r < 4; ++r)
        G[(wave * 16 + rq + r) * GSTR + 16 + col] = acc1[r];
    }
  }
  if ((tid & 3) == 0) G[srow * GSTR + 24] = xn;
  if (wave == 0 && lane < 16) WN[lane] = wn0;
  if (wave == 0 && lane < 8)  WN[16 + lane] = wn1;
  if (tid < 8) BI[tid] = breg;

  __syncthreads();

  // ---- phase 2: DTW per (p, f); branchless backtrace ----
  #pragma unroll
  for (int it = 0; it < 2; ++it) {
    const int o = tid + it * 128;
    if (o < TT * 8) {
      const int pl = o >> 3, f = o & 7;
      const int p  = p0 + pl;

      float xnv[3], dots[3][3], D[3][3];
      #pragma unroll
      for (int i = 0; i < 3; ++i) {
        xnv[i] = G[(pl + i) * GSTR + 24];
        #pragma unroll
        for (int j = 0; j < 3; ++j) dots[i][j] = G[(pl + i) * GSTR + j * 8 + f];
      }
      #pragma unroll
      for (int i = 0; i < 3; ++i) {
        #pragma unroll
        for (int j = 0; j < 3; ++j) {
          const float sq = xnv[i] + WN[j * 8 + f] - 2.f * dots[i][j];
          D[i][j] = sqrtf(fmaxf(sq, 0.f));
        }
      }

      // forward DP + 2-bit choice LUT (first-min argmin semantics)
      float cost[4][4];
      cost[0][0] = 0.f; cost[0][1] = BIGV; cost[0][2] = BIGV; cost[0][3] = BIGV;
      unsigned M = 0;
      #pragma unroll
      for (int i = 1; i <= 3; ++i) {
        cost[i][0] = BIGV;
        #pragma unroll
        for (int j = 1; j <= 3; ++j) {
          const float ca = cost[i-1][j-1], cb = cost[i][j-1], cc = cost[i-1][j];
          const int m = (ca <= cb) ? ((ca <= cc) ? 0 : 2) : ((cb <= cc) ? 1 : 2);
          cost[i][j] = D[i-1][j-1] + fminf(fminf(cb, ca), cc);
          M |= (unsigned)m << (2 * (i * 4 + j));
        }
      }

      // branchless backtrace, 5 steps
      float acc = dots[2][2];
      int ii = 3, jj = 3;
      bool act = true;
      #pragma unroll
      for (int s = 0; s < 5; ++s) {
        const unsigned st = ((unsigned)(ii & 3) << 2) | (unsigned)(jj & 3);
        const int m  = (M >> (2 * st)) & 3;
        const int i2 = ii - ((m == 1) ? 0 : 1);
        const int j2 = jj - ((m == 2) ? 0 : 1);
        const bool nxt = act && (i2 > 0) && (j2 > 0);
        const int ia = (i2 > 1) ? i2 - 1 : 0;
        const int ja = (j2 > 1) ? j2 - 1 : 0;
        const float v =
            (ia == 0) ? ((ja == 0) ? dots[0][0] : (ja == 1) ? dots[0][1] : dots[0][2])
          : (ia == 1) ? ((ja == 0) ? dots[1][0] : (ja == 1) ? dots[1][1] : dots[1][2])
                      : ((ja == 0) ? dots[2][0] : (ja == 1) ? dots[2][1] : dots[2][2]);
        acc += nxt ? v : 0.f;
        ii = i2; jj = j2; act = nxt;
      }

      if (p < P) out[((size_t)b * P + p) * 8 + f] = fmaxf(acc + BI[f], 0.f);
    }
  }
}

extern "C" void kernel_launch(void* const* d_in, const int* in_sizes, int n_in,
                              void* d_out, int out_size, void* d_ws, size_t ws_size,
                              hipStream_t stream) {
  const float* x    = (const float*)d_in[0];
  const float* w    = (const float*)d_in[1];
  const float* bias = (const float*)d_in[2];
  float* out        = (float*)d_out;

  dim3 grid(69, 32);  // ceil(2046/30) x B
  dwa_cnn_kernel<<<grid, 128, 0, stream>>>(x, w, bias, out);
}